// Round 1
// baseline (323.899 us; speedup 1.0000x reference)
//
#include <hip/hip_runtime.h>
#include <hip/hip_bf16.h>
#include <cstdint>
#include <cstddef>

// ---------------------------------------------------------------------------
// Cross attention, B=8 N=1024 C=768 HEADS=8 HD=96, sr_ratio=1 path.
// Pipeline (all matmul in bf16 MFMA 16x16x32, fp32 accumulate):
//   1. cvt: x,y,Wq,Wk,Wv,Wp  f32 -> bf16 workspace
//   2. GEMM Q = x@Wq^T  -> bf16 [B][N][C]
//      GEMM K = y@Wk^T  -> bf16 [B][N][C]
//      GEMM V = y@Wv^T  -> bf16 transposed [B][H][HD][N]  (for clean PV B-frags)
//   3. flash attention (64-row Q tile/block, online softmax, rel_pos bias)
//      -> AO bf16 [B][N][C]
//   4. GEMM out = AO@Wp^T + bp -> f32 d_out
// ---------------------------------------------------------------------------

using f32x4  = __attribute__((ext_vector_type(4))) float;
using bf16x8 = __attribute__((ext_vector_type(8))) __bf16;

constexpr int Bb = 8, Nn = 1024, Cc = 768, Hh = 8, HD = 96;
constexpr float SCALE = 0.10206207261596575f;  // 96^-0.5

__device__ __forceinline__ uint16_t f2bf(float f) {
  union { float f; uint32_t u; } v; v.f = f;
  return (uint16_t)((v.u + 0x7fffu + ((v.u >> 16) & 1u)) >> 16);  // RNE
}

__device__ __forceinline__ void gl_lds16(const void* g, void* l) {
  // async 16B/lane global->LDS; LDS dest must be wave-uniform base + lane*16
  __builtin_amdgcn_global_load_lds(
      (const __attribute__((address_space(1))) void*)g,
      (__attribute__((address_space(3))) void*)l, 16, 0, 0);
}

__device__ __forceinline__ f32x4 mfma16(bf16x8 a, bf16x8 b, f32x4 c) {
  return __builtin_amdgcn_mfma_f32_16x16x32_bf16(a, b, c, 0, 0, 0);
}

// ---------------------------------------------------------------------------
__global__ void cvt_kernel(const float* __restrict__ src,
                           uint16_t* __restrict__ dst, int n4) {
  int i = blockIdx.x * blockDim.x + threadIdx.x;
  if (i < n4) {
    float4 v = ((const float4*)src)[i];
    ushort4 o;
    o.x = f2bf(v.x); o.y = f2bf(v.y); o.z = f2bf(v.z); o.w = f2bf(v.w);
    ((ushort4*)dst)[i] = o;
  }
}

// ---------------------------------------------------------------------------
// GEMM: D[m][n] = sum_k A[m][k] * Bt[n][k],  M=8192, N=768, K=768.
// 128x128 tile, BK=32, 256 threads (4 waves, each 64x64 quadrant, 4x4 MFMAs).
// MODE 0: bf16 out, natural [M][768]
// MODE 1: bf16 out, scattered to Vt[B][H][HD][N]
// MODE 2: f32 out + bias (final projection)
template <int MODE>
__global__ __launch_bounds__(256, 2) void gemm_kernel(
    const uint16_t* __restrict__ A, const uint16_t* __restrict__ Bt,
    void* __restrict__ outp, const float* __restrict__ bias) {
  constexpr int K = 768;
  __shared__ uint16_t As[128 * 32];
  __shared__ uint16_t Bs[128 * 32];
  const int tid = threadIdx.x;
  const int m0 = blockIdx.y * 128;
  const int n0 = blockIdx.x * 128;
  const int w = tid >> 6, lane = tid & 63;
  const int l16 = lane & 15, quad = lane >> 4;
  const int wm = (w & 1) * 64, wn = (w >> 1) * 64;

  f32x4 acc[4][4] = {};

  const int c0 = tid, c1 = tid + 256;            // 512 chunks of 16B per tile
  const int r0 = c0 >> 2, cc0 = (c0 & 3) * 8;
  const int r1 = c1 >> 2, cc1 = (c1 & 3) * 8;

  for (int k0 = 0; k0 < K; k0 += 32) {
    __syncthreads();  // prior-iter LDS reads done
    gl_lds16(A + (size_t)(m0 + r0) * K + k0 + cc0, &As[c0 * 8]);
    gl_lds16(A + (size_t)(m0 + r1) * K + k0 + cc1, &As[c1 * 8]);
    gl_lds16(Bt + (size_t)(n0 + r0) * K + k0 + cc0, &Bs[c0 * 8]);
    gl_lds16(Bt + (size_t)(n0 + r1) * K + k0 + cc1, &Bs[c1 * 8]);
    __syncthreads();  // compiler drains vmcnt before barrier

    bf16x8 a[4], b[4];
#pragma unroll
    for (int i = 0; i < 4; ++i)
      a[i] = *(const bf16x8*)&As[(wm + i * 16 + l16) * 32 + quad * 8];
#pragma unroll
    for (int j = 0; j < 4; ++j)
      b[j] = *(const bf16x8*)&Bs[(wn + j * 16 + l16) * 32 + quad * 8];
#pragma unroll
    for (int i = 0; i < 4; ++i)
#pragma unroll
      for (int j = 0; j < 4; ++j)
        acc[i][j] = mfma16(a[i], b[j], acc[i][j]);
  }

  if (MODE == 0) {
    uint16_t* O = (uint16_t*)outp;
#pragma unroll
    for (int i = 0; i < 4; ++i)
#pragma unroll
      for (int j = 0; j < 4; ++j) {
        int col = n0 + wn + j * 16 + l16;
#pragma unroll
        for (int r = 0; r < 4; ++r) {
          int row = m0 + wm + i * 16 + quad * 4 + r;
          O[(size_t)row * 768 + col] = f2bf(acc[i][j][r]);
        }
      }
  } else if (MODE == 1) {
    uint16_t* O = (uint16_t*)outp;
#pragma unroll
    for (int i = 0; i < 4; ++i) {
      int row0 = m0 + wm + i * 16 + quad * 4;  // 4 consecutive rows (same batch)
      int bidx = row0 >> 10, nseq = row0 & 1023;
#pragma unroll
      for (int j = 0; j < 4; ++j) {
        int col = n0 + wn + j * 16 + l16;
        int h = col / 96, hd = col % 96;
        ushort4 pk;
        pk.x = f2bf(acc[i][j][0]); pk.y = f2bf(acc[i][j][1]);
        pk.z = f2bf(acc[i][j][2]); pk.w = f2bf(acc[i][j][3]);
        size_t o = (((size_t)(bidx * 8 + h) * 96 + hd) << 10) + nseq;
        *(ushort4*)(O + o) = pk;
      }
    }
  } else {
    float* O = (float*)outp;
    float bv[4];
#pragma unroll
    for (int j = 0; j < 4; ++j) bv[j] = bias[n0 + wn + j * 16 + l16];
#pragma unroll
    for (int i = 0; i < 4; ++i)
#pragma unroll
      for (int j = 0; j < 4; ++j) {
        int col = n0 + wn + j * 16 + l16;
#pragma unroll
        for (int r = 0; r < 4; ++r) {
          int row = m0 + wm + i * 16 + quad * 4 + r;
          O[(size_t)row * 768 + col] = acc[i][j][r] + bv[j];
        }
      }
  }
}

// ---------------------------------------------------------------------------
// Flash attention. Grid (16, 64): x = q-tile (64 rows), y = b*8+h.
// 256 threads = 4 waves; wave w owns q-rows [16w,16w+16) of the tile.
// K/V tiles of 64 rows; online softmax state per q-row in registers.
__global__ __launch_bounds__(256, 2) void attn_kernel(
    const uint16_t* __restrict__ Q,   // [B][N][C] bf16
    const uint16_t* __restrict__ Kb,  // [B][N][C] bf16
    const uint16_t* __restrict__ Vt,  // [B][H][HD][N] bf16
    const float* __restrict__ rel,    // [H][N][N] f32
    uint16_t* __restrict__ AO) {      // [B][N][C] bf16
  __shared__ uint16_t Qs[64 * 96];   // 12 KB
  __shared__ uint16_t Ks[64 * 96];   // 12 KB
  __shared__ uint16_t Vs[96 * 64];   // 12 KB, XOR-swizzled 16B chunks
  __shared__ uint16_t Ps[64 * 80];   // 10 KB, stride 80 (16B-aligned rows)

  const int tid = threadIdx.x;
  const int q0 = blockIdx.x * 64;
  const int bh = blockIdx.y;
  const int b = bh >> 3, h = bh & 7;
  const int w = tid >> 6, lane = tid & 63;
  const int l16 = lane & 15, quad = lane >> 4;

  // stage Q tile once: 64 rows x 96 bf16 = 768 16B chunks
#pragma unroll
  for (int i = 0; i < 3; ++i) {
    int c = tid + 256 * i;
    int row = c / 12, cc = c % 12;
    gl_lds16(Q + ((size_t)(b * 1024 + q0 + row) * 768 + h * 96 + cc * 8),
             &Qs[c * 8]);
  }

  float m_i[4], l_i[4];
#pragma unroll
  for (int r = 0; r < 4; ++r) { m_i[r] = -1e30f; l_i[r] = 0.f; }
  f32x4 o_acc[6] = {};

  const int qrow_base = q0 + w * 16 + quad * 4;

  for (int kt = 0; kt < 16; ++kt) {
    const int k0 = kt * 64;
    __syncthreads();  // prior-iter LDS reads done (also covers Q staging)
#pragma unroll
    for (int i = 0; i < 3; ++i) {
      int c = tid + 256 * i;
      int row = c / 12, cc = c % 12;
      gl_lds16(Kb + ((size_t)(b * 1024 + k0 + row) * 768 + h * 96 + cc * 8),
               &Ks[c * 8]);
    }
#pragma unroll
    for (int i = 0; i < 3; ++i) {
      int c = tid + 256 * i;
      int d = c >> 3, mcs = c & 7;
      int mc = (mcs - d) & 7;  // physical chunk mcs holds logical chunk mc
      gl_lds16(Vt + ((size_t)((b * 8 + h) * 96 + d) * 1024 + k0 + mc * 8),
               &Vs[c * 8]);
    }
    __syncthreads();

    // S strip (16x64) = Q_strip (16x96) @ K_tile^T
    f32x4 s[4] = {};
#pragma unroll
    for (int ks = 0; ks < 96; ks += 32) {
      bf16x8 a = *(const bf16x8*)&Qs[(w * 16 + l16) * 96 + ks + quad * 8];
#pragma unroll
      for (int nt = 0; nt < 4; ++nt) {
        bf16x8 bb = *(const bf16x8*)&Ks[(nt * 16 + l16) * 96 + ks + quad * 8];
        s[nt] = mfma16(a, bb, s[nt]);
      }
    }

    // scale + relative-position bias
    float sv[4][4];
#pragma unroll
    for (int r = 0; r < 4; ++r) {
      const float* rp =
          rel + ((size_t)h * 1024 + qrow_base + r) * 1024 + k0 + l16;
#pragma unroll
      for (int nt = 0; nt < 4; ++nt)
        sv[nt][r] = s[nt][r] * SCALE + rp[nt * 16];
    }

    // online softmax per row (row owned by 16 lanes of one quad-group)
#pragma unroll
    for (int r = 0; r < 4; ++r) {
      float mx = fmaxf(fmaxf(sv[0][r], sv[1][r]), fmaxf(sv[2][r], sv[3][r]));
#pragma unroll
      for (int off = 1; off < 16; off <<= 1)
        mx = fmaxf(mx, __shfl_xor(mx, off));
      float mnew = fmaxf(m_i[r], mx);
      float alpha = __expf(m_i[r] - mnew);
      m_i[r] = mnew;
      float rs = 0.f;
#pragma unroll
      for (int nt = 0; nt < 4; ++nt) {
        float p = __expf(sv[nt][r] - mnew);
        sv[nt][r] = p;
        rs += p;
      }
#pragma unroll
      for (int off = 1; off < 16; off <<= 1) rs += __shfl_xor(rs, off);
      l_i[r] = l_i[r] * alpha + rs;
#pragma unroll
      for (int jt = 0; jt < 6; ++jt) o_acc[jt][r] *= alpha;
    }

    // P (C-layout) -> LDS (A-layout source), wave-local rows only
#pragma unroll
    for (int r = 0; r < 4; ++r)
#pragma unroll
      for (int nt = 0; nt < 4; ++nt)
        Ps[(w * 16 + quad * 4 + r) * 80 + nt * 16 + l16] = f2bf(sv[nt][r]);
    asm volatile("s_waitcnt lgkmcnt(0)" ::: "memory");  // wave-internal ordering

    // O strip (16x96) += P strip (16x64) @ V tile (64x96)
#pragma unroll
    for (int ks = 0; ks < 64; ks += 32) {
      bf16x8 a = *(const bf16x8*)&Ps[(w * 16 + l16) * 80 + ks + quad * 8];
#pragma unroll
      for (int jt = 0; jt < 6; ++jt) {
        int d = jt * 16 + l16;
        int mcs = ((ks >> 3) + quad + d) & 7;  // un-swizzle
        bf16x8 bb = *(const bf16x8*)&Vs[d * 64 + mcs * 8];
        o_acc[jt] = mfma16(a, bb, o_acc[jt]);
      }
    }
  }

  // epilogue: normalize and store bf16
#pragma unroll
  for (int r = 0; r < 4; ++r) {
    float inv = 1.f / l_i[r];
    int row = qrow_base + r;
#pragma unroll
    for (int jt = 0; jt < 6; ++jt) {
      int col = h * 96 + jt * 16 + l16;
      AO[(size_t)(b * 1024 + row) * 768 + col] = f2bf(o_acc[jt][r] * inv);
    }
  }
}

// ---------------------------------------------------------------------------
extern "C" void kernel_launch(void* const* d_in, const int* in_sizes, int n_in,
                              void* d_out, int out_size, void* d_ws,
                              size_t ws_size, hipStream_t stream) {
  const float* x   = (const float*)d_in[0];
  const float* y   = (const float*)d_in[1];
  const float* rel = (const float*)d_in[2];
  const float* Wq  = (const float*)d_in[5];
  const float* Wk  = (const float*)d_in[6];
  const float* Wv  = (const float*)d_in[7];
  const float* Wp  = (const float*)d_in[8];
  const float* bp  = (const float*)d_in[9];
  float* out = (float*)d_out;

  const size_t nBNC = (size_t)Bb * Nn * Cc;  // 6291456
  const size_t nW = (size_t)Cc * Cc;         // 589824

  char* ws = (char*)d_ws;
  size_t off = 0;
  auto alloc = [&](size_t bytes) {
    char* p = ws + off;
    off += (bytes + 255) & ~(size_t)255;
    return p;
  };
  uint16_t* xb  = (uint16_t*)alloc(nBNC * 2);
  uint16_t* yb  = (uint16_t*)alloc(nBNC * 2);
  uint16_t* wqb = (uint16_t*)alloc(nW * 2);
  uint16_t* wkb = (uint16_t*)alloc(nW * 2);
  uint16_t* wvb = (uint16_t*)alloc(nW * 2);
  uint16_t* wpb = (uint16_t*)alloc(nW * 2);
  uint16_t* Qb  = (uint16_t*)alloc(nBNC * 2);
  uint16_t* Kb  = (uint16_t*)alloc(nBNC * 2);
  uint16_t* Vtb = (uint16_t*)alloc(nBNC * 2);
  uint16_t* AOb = (uint16_t*)alloc(nBNC * 2);

  // 1. f32 -> bf16
  cvt_kernel<<<(int)(nBNC / 4 / 256), 256, 0, stream>>>(x, xb, (int)(nBNC / 4));
  cvt_kernel<<<(int)(nBNC / 4 / 256), 256, 0, stream>>>(y, yb, (int)(nBNC / 4));
  cvt_kernel<<<(int)(nW / 4 / 256), 256, 0, stream>>>(Wq, wqb, (int)(nW / 4));
  cvt_kernel<<<(int)(nW / 4 / 256), 256, 0, stream>>>(Wk, wkb, (int)(nW / 4));
  cvt_kernel<<<(int)(nW / 4 / 256), 256, 0, stream>>>(Wv, wvb, (int)(nW / 4));
  cvt_kernel<<<(int)(nW / 4 / 256), 256, 0, stream>>>(Wp, wpb, (int)(nW / 4));

  // 2. projections (M=8192, N=768 -> grid 6x64)
  dim3 ggrid(6, 64);
  gemm_kernel<0><<<ggrid, 256, 0, stream>>>(xb, wqb, Qb, nullptr);
  gemm_kernel<0><<<ggrid, 256, 0, stream>>>(yb, wkb, Kb, nullptr);
  gemm_kernel<1><<<ggrid, 256, 0, stream>>>(yb, wvb, Vtb, nullptr);

  // 3. attention
  attn_kernel<<<dim3(16, 64), 256, 0, stream>>>(Qb, Kb, Vtb, rel, AOb);

  // 4. output projection + bias
  gemm_kernel<2><<<ggrid, 256, 0, stream>>>(AOb, wpb, out, bp);
}

// Round 2
// 260.283 us; speedup vs baseline: 1.2444x; 1.2444x over previous
//
#include <hip/hip_runtime.h>
#include <hip/hip_bf16.h>
#include <cstdint>
#include <cstddef>

// ---------------------------------------------------------------------------
// Cross attention, B=8 N=1024 C=768 HEADS=8 HD=96, sr_ratio=1 path.
//   1. cvt: x,y -> bf16; Wq*SCALE*log2e, Wk, Wv, Wp -> bf16
//   2. fused QKV GEMM (bf16 MFMA 16x16x32, BK=64, XOR-swizzled LDS)
//      Q,K -> [B][N][C] bf16 ; V -> transposed [B*H][HD][N] bf16
//   3. flash attention: 64-q-row tile/block, reg-resident Q frags,
//      DPP row_ror softmax reductions, exp2 domain, online softmax
//   4. proj GEMM out = AO@Wp^T + bp -> f32
// ---------------------------------------------------------------------------

using f32x4  = __attribute__((ext_vector_type(4))) float;
using bf16x8 = __attribute__((ext_vector_type(8))) __bf16;

constexpr int Bb = 8, Nn = 1024, Cc = 768;
constexpr float LOG2E = 1.4426950408889634f;
constexpr float QSC   = 0.10206207261596575f * 1.4426950408889634f;  // SCALE*log2e

__device__ __forceinline__ uint16_t f2bf(float f) {
  union { float f; uint32_t u; } v; v.f = f;
  return (uint16_t)((v.u + 0x7fffu + ((v.u >> 16) & 1u)) >> 16);  // RNE
}

__device__ __forceinline__ void gl_lds16(const void* g, void* l) {
  __builtin_amdgcn_global_load_lds(
      (const __attribute__((address_space(1))) void*)g,
      (__attribute__((address_space(3))) void*)l, 16, 0, 0);
}

__device__ __forceinline__ f32x4 mfma16(bf16x8 a, bf16x8 b, f32x4 c) {
  return __builtin_amdgcn_mfma_f32_16x16x32_bf16(a, b, c, 0, 0, 0);
}

// DPP row_ror reduction helpers (16-lane row = one quad group's domain)
template <int CTRL>
__device__ __forceinline__ float dpp_max(float v) {
  union { float f; int i; } u, r;
  u.f = v;
  r.i = __builtin_amdgcn_update_dpp(u.i, u.i, CTRL, 0xF, 0xF, false);
  return fmaxf(v, r.f);
}
template <int CTRL>
__device__ __forceinline__ float dpp_add(float v) {
  union { float f; int i; } u, r;
  u.f = v;
  r.i = __builtin_amdgcn_update_dpp(u.i, u.i, CTRL, 0xF, 0xF, false);
  return v + r.f;
}
__device__ __forceinline__ float red16_max(float v) {
  v = dpp_max<0x128>(v);  // row_ror:8
  v = dpp_max<0x124>(v);  // row_ror:4
  v = dpp_max<0x122>(v);  // row_ror:2
  v = dpp_max<0x121>(v);  // row_ror:1
  return v;
}
__device__ __forceinline__ float red16_add(float v) {
  v = dpp_add<0x128>(v);
  v = dpp_add<0x124>(v);
  v = dpp_add<0x122>(v);
  v = dpp_add<0x121>(v);
  return v;
}

// ---------------------------------------------------------------------------
__global__ void cvt2_kernel(const float* __restrict__ a,
                            const float* __restrict__ b,
                            uint16_t* __restrict__ da,
                            uint16_t* __restrict__ db, int n4) {
  int i = blockIdx.x * blockDim.x + threadIdx.x;
  const float* s = blockIdx.y ? b : a;
  uint16_t* d = blockIdx.y ? db : da;
  if (i < n4) {
    float4 v = ((const float4*)s)[i];
    ushort4 o;
    o.x = f2bf(v.x); o.y = f2bf(v.y); o.z = f2bf(v.z); o.w = f2bf(v.w);
    ((ushort4*)d)[i] = o;
  }
}

__global__ void cvtw_kernel(const float* __restrict__ wq,
                            const float* __restrict__ wk,
                            const float* __restrict__ wv,
                            const float* __restrict__ wp,
                            uint16_t* __restrict__ dq, uint16_t* __restrict__ dk,
                            uint16_t* __restrict__ dv, uint16_t* __restrict__ dp,
                            int n4) {
  int i = blockIdx.x * blockDim.x + threadIdx.x;
  const float* s; uint16_t* d; float sc = 1.f;
  switch (blockIdx.y) {
    case 0:  s = wq; d = dq; sc = QSC; break;  // fold SCALE*log2e into Wq
    case 1:  s = wk; d = dk; break;
    case 2:  s = wv; d = dv; break;
    default: s = wp; d = dp; break;
  }
  if (i < n4) {
    float4 v = ((const float4*)s)[i];
    ushort4 o;
    o.x = f2bf(v.x * sc); o.y = f2bf(v.y * sc);
    o.z = f2bf(v.z * sc); o.w = f2bf(v.w * sc);
    ((ushort4*)d)[i] = o;
  }
}

// ---------------------------------------------------------------------------
// GEMM core: 128x128 tile, BK=64, XOR-swizzled 16B chunks (conflict-free
// ds_read_b128), M=8192 N=768 K=768, A row-major, Bt row-major (B^T).
__device__ __forceinline__ void gemm_core(const uint16_t* __restrict__ A,
                                          const uint16_t* __restrict__ Bt,
                                          int m0, int n0, f32x4 (&acc)[4][4]) {
  __shared__ uint16_t As[128 * 64];
  __shared__ uint16_t Bs[128 * 64];
  const int tid = threadIdx.x;
  const int lane = tid & 63, l16 = lane & 15, quad = lane >> 4;
  const int w = tid >> 6;
  const int wm = (w & 1) * 64, wn = (w >> 1) * 64;

  int soff[4];
#pragma unroll
  for (int i = 0; i < 4; ++i) {
    int idx = tid + 256 * i;
    int row = idx >> 3, pc = idx & 7;
    int c = pc ^ (row & 7);           // logical chunk staged at phys pc
    soff[i] = row * 768 + c * 8;
  }

  for (int k0 = 0; k0 < 768; k0 += 64) {
    __syncthreads();
#pragma unroll
    for (int i = 0; i < 4; ++i)
      gl_lds16(A + (size_t)m0 * 768 + k0 + soff[i], &As[(tid + 256 * i) * 8]);
#pragma unroll
    for (int i = 0; i < 4; ++i)
      gl_lds16(Bt + (size_t)n0 * 768 + k0 + soff[i], &Bs[(tid + 256 * i) * 8]);
    __syncthreads();

#pragma unroll
    for (int ks = 0; ks < 2; ++ks) {
      bf16x8 a[4], b[4];
      const int phys = (ks * 4 + quad) ^ (l16 & 7);
#pragma unroll
      for (int i = 0; i < 4; ++i)
        a[i] = *(const bf16x8*)&As[(wm + i * 16 + l16) * 64 + phys * 8];
#pragma unroll
      for (int j = 0; j < 4; ++j)
        b[j] = *(const bf16x8*)&Bs[(wn + j * 16 + l16) * 64 + phys * 8];
#pragma unroll
      for (int i = 0; i < 4; ++i)
#pragma unroll
        for (int j = 0; j < 4; ++j)
          acc[i][j] = mfma16(a[i], b[j], acc[i][j]);
    }
  }
}

// Fused Q/K/V projections. Grid (18,64): x/6 -> segment {Q,K,V}.
__global__ __launch_bounds__(256, 3) void qkv_kernel(
    const uint16_t* __restrict__ xb, const uint16_t* __restrict__ yb,
    const uint16_t* __restrict__ wq, const uint16_t* __restrict__ wk,
    const uint16_t* __restrict__ wv, uint16_t* __restrict__ Qb,
    uint16_t* __restrict__ Kb, uint16_t* __restrict__ Vt) {
  const int seg = blockIdx.x / 6, nb = blockIdx.x % 6;
  const uint16_t* A  = (seg == 0) ? xb : yb;
  const uint16_t* Bt = (seg == 0) ? wq : (seg == 1) ? wk : wv;
  const int m0 = blockIdx.y * 128, n0 = nb * 128;

  f32x4 acc[4][4] = {};
  gemm_core(A, Bt, m0, n0, acc);

  const int tid = threadIdx.x, lane = tid & 63;
  const int l16 = lane & 15, quad = lane >> 4, w = tid >> 6;
  const int wm = (w & 1) * 64, wn = (w >> 1) * 64;

  if (seg <= 1) {
    uint16_t* O = seg ? Kb : Qb;
#pragma unroll
    for (int i = 0; i < 4; ++i)
#pragma unroll
      for (int j = 0; j < 4; ++j) {
        int col = n0 + wn + j * 16 + l16;
#pragma unroll
        for (int r = 0; r < 4; ++r) {
          int row = m0 + wm + i * 16 + quad * 4 + r;
          O[(size_t)row * 768 + col] = f2bf(acc[i][j][r]);
        }
      }
  } else {
    // V scatter: Vt[b*8+h][hd][n]
#pragma unroll
    for (int i = 0; i < 4; ++i) {
      int row0 = m0 + wm + i * 16 + quad * 4;
      int bidx = row0 >> 10, nseq = row0 & 1023;
#pragma unroll
      for (int j = 0; j < 4; ++j) {
        int col = n0 + wn + j * 16 + l16;
        int h = col / 96, hd = col % 96;
        ushort4 pk;
        pk.x = f2bf(acc[i][j][0]); pk.y = f2bf(acc[i][j][1]);
        pk.z = f2bf(acc[i][j][2]); pk.w = f2bf(acc[i][j][3]);
        size_t o = (((size_t)(bidx * 8 + h) * 96 + hd) << 10) + nseq;
        *(ushort4*)(Vt + o) = pk;
      }
    }
  }
}

// Output projection: out = AO@Wp^T + bp (f32). Grid (6,64).
__global__ __launch_bounds__(256, 3) void proj_kernel(
    const uint16_t* __restrict__ A, const uint16_t* __restrict__ Bt,
    float* __restrict__ out, const float* __restrict__ bias) {
  const int m0 = blockIdx.y * 128, n0 = blockIdx.x * 128;
  f32x4 acc[4][4] = {};
  gemm_core(A, Bt, m0, n0, acc);

  const int tid = threadIdx.x, lane = tid & 63;
  const int l16 = lane & 15, quad = lane >> 4, w = tid >> 6;
  const int wm = (w & 1) * 64, wn = (w >> 1) * 64;
  float bv[4];
#pragma unroll
  for (int j = 0; j < 4; ++j) bv[j] = bias[n0 + wn + j * 16 + l16];
#pragma unroll
  for (int i = 0; i < 4; ++i)
#pragma unroll
    for (int j = 0; j < 4; ++j) {
      int col = n0 + wn + j * 16 + l16;
#pragma unroll
      for (int r = 0; r < 4; ++r) {
        int row = m0 + wm + i * 16 + quad * 4 + r;
        out[(size_t)row * 768 + col] = acc[i][j][r] + bv[j];
      }
    }
}

// ---------------------------------------------------------------------------
// Flash attention. Grid (16, 64): x = q-tile (64 rows), y = b*8+h.
// 4 waves; wave w owns q-rows [16w,16w+16). Q frags in registers.
// Scores already in log2 domain (SCALE*log2e folded into Wq; rel*log2e at use).
__global__ __launch_bounds__(256, 4) void attn_kernel(
    const uint16_t* __restrict__ Q,   // [B][N][C] bf16 (pre-scaled)
    const uint16_t* __restrict__ Kb,  // [B][N][C] bf16
    const uint16_t* __restrict__ Vt,  // [B*H][HD][N] bf16
    const float* __restrict__ rel,    // [H][N][N] f32
    uint16_t* __restrict__ AO) {      // [B][N][C] bf16
  __shared__ uint16_t Ks[64 * 96];   // 12 KB, 12 chunk/row, mixed-XOR swizzle
  __shared__ uint16_t Vs[96 * 64];   // 12 KB, 8 chunk/row, XOR swizzle
  __shared__ uint16_t Ps[64 * 64];   // 8 KB,  8 chunk/row, XOR swizzle

  const int tid = threadIdx.x;
  const int q0 = blockIdx.x * 64;
  const int bh = blockIdx.y;
  const int b = bh >> 3, h = bh & 7;
  const int w = tid >> 6, lane = tid & 63;
  const int l16 = lane & 15, quad = lane >> 4;
  const int l7 = l16 & 7;

  // Q fragments in registers: A-frag lane l16 -> q-row w*16+l16
  const int qrow = q0 + w * 16 + l16;
  bf16x8 qf[3];
  {
    const uint16_t* qp =
        Q + ((size_t)(b * 1024 + qrow)) * 768 + h * 96 + quad * 8;
#pragma unroll
    for (int j = 0; j < 3; ++j) qf[j] = *(const bf16x8*)(qp + j * 32);
  }

  // staging source offsets (within (b,k0) slab)
  int koff[3], voff[3];
#pragma unroll
  for (int i = 0; i < 3; ++i) {
    int idx = tid + 256 * i;
    int krow = idx / 12, kpc = idx % 12;
    int kc = (kpc < 8) ? (kpc ^ (krow & 7)) : (8 + ((kpc & 3) ^ (krow & 3)));
    koff[i] = krow * 768 + kc * 8;
    int d = idx >> 3, vpc = idx & 7;
    int vc = vpc ^ (d & 7);
    voff[i] = d * 1024 + vc * 8;
  }

  float m_i[4], l_i[4];
#pragma unroll
  for (int r = 0; r < 4; ++r) { m_i[r] = -1e30f; l_i[r] = 0.f; }
  f32x4 o_acc[6] = {};

  const float* relbase =
      rel + ((size_t)h << 20) + ((size_t)(q0 + w * 16 + quad * 4) << 10) + l16;
  const uint16_t* kslab = Kb + ((size_t)(b * 1024)) * 768 + h * 96;
  const uint16_t* vslab = Vt + ((size_t)(bh * 96) << 10);

  for (int kt = 0; kt < 16; ++kt) {
    const int k0 = kt * 64;
    __syncthreads();  // prior-iter LDS reads done
#pragma unroll
    for (int i = 0; i < 3; ++i)
      gl_lds16(kslab + (size_t)k0 * 768 + koff[i], &Ks[(tid + 256 * i) * 8]);
#pragma unroll
    for (int i = 0; i < 3; ++i)
      gl_lds16(vslab + k0 + voff[i], &Vs[(tid + 256 * i) * 8]);

    // prefetch rel bias into regs (latency overlaps staging + MFMAs)
    float relv[16];
#pragma unroll
    for (int r = 0; r < 4; ++r)
#pragma unroll
      for (int nt = 0; nt < 4; ++nt)
        relv[nt * 4 + r] = relbase[(size_t)r * 1024 + k0 + nt * 16];

    __syncthreads();  // staging drained (vmcnt(0) before barrier)

    // S strip (16 q x 64 k): Q regs (A) x K tile (B)
    f32x4 s[4] = {};
#pragma unroll
    for (int ksi = 0; ksi < 3; ++ksi) {
#pragma unroll
      for (int nt = 0; nt < 4; ++nt) {
        const int row = nt * 16 + l16;
        const int c = ksi * 4 + quad;
        const int phys =
            (ksi < 2) ? (c ^ (row & 7)) : (8 + ((c & 3) ^ (row & 3)));
        bf16x8 kf = *(const bf16x8*)&Ks[row * 96 + phys * 8];
        s[nt] = mfma16(qf[ksi], kf, s[nt]);
      }
    }

    // bias add (log2 domain)
    float vals[16];
#pragma unroll
    for (int nt = 0; nt < 4; ++nt)
#pragma unroll
      for (int r = 0; r < 4; ++r)
        vals[nt * 4 + r] = fmaf(relv[nt * 4 + r], LOG2E, s[nt][r]);

    // online softmax, one row per (quad,r); 16-lane DPP reductions
#pragma unroll
    for (int r = 0; r < 4; ++r) {
      float mx = fmaxf(fmaxf(vals[r], vals[4 + r]),
                       fmaxf(vals[8 + r], vals[12 + r]));
      mx = red16_max(mx);
      float mnew = fmaxf(m_i[r], mx);
      float alpha = __builtin_amdgcn_exp2f(m_i[r] - mnew);
      m_i[r] = mnew;
      float p0 = __builtin_amdgcn_exp2f(vals[r] - mnew);
      float p1 = __builtin_amdgcn_exp2f(vals[4 + r] - mnew);
      float p2 = __builtin_amdgcn_exp2f(vals[8 + r] - mnew);
      float p3 = __builtin_amdgcn_exp2f(vals[12 + r] - mnew);
      vals[r] = p0; vals[4 + r] = p1; vals[8 + r] = p2; vals[12 + r] = p3;
      float rs = red16_add((p0 + p1) + (p2 + p3));
      l_i[r] = l_i[r] * alpha + rs;
#pragma unroll
      for (int jt = 0; jt < 6; ++jt) o_acc[jt][r] *= alpha;
    }

    // P (C-layout) -> Ps, wave-local rows, XOR-swizzled chunks
    const int khi = l16 >> 3;
#pragma unroll
    for (int r = 0; r < 4; ++r) {
      const int qloc = quad * 4 + r;
      const int rowoff = (w * 16 + qloc) * 64;
      const int sw = qloc & 7;
#pragma unroll
      for (int nt = 0; nt < 4; ++nt) {
        const int kc = 2 * nt + khi;
        Ps[rowoff + (((kc ^ sw) << 3) | l7)] = f2bf(vals[nt * 4 + r]);
      }
    }
    asm volatile("s_waitcnt lgkmcnt(0)" ::: "memory");  // wave-internal W->R

    // O strip (16 q x 96 d) += P (A) x V (B)
#pragma unroll
    for (int ksi = 0; ksi < 2; ++ksi) {
      const int c = ksi * 4 + quad;
      const int phys = c ^ l7;
      bf16x8 pf = *(const bf16x8*)&Ps[(w * 16 + l16) * 64 + phys * 8];
#pragma unroll
      for (int jt = 0; jt < 6; ++jt) {
        const int d = jt * 16 + l16;
        bf16x8 vf = *(const bf16x8*)&Vs[d * 64 + phys * 8];  // d&7 == l7
        o_acc[jt] = mfma16(pf, vf, o_acc[jt]);
      }
    }
  }

  // epilogue
#pragma unroll
  for (int r = 0; r < 4; ++r) {
    float inv = 1.f / l_i[r];
    int row = q0 + w * 16 + quad * 4 + r;
#pragma unroll
    for (int jt = 0; jt < 6; ++jt) {
      int col = h * 96 + jt * 16 + l16;
      AO[(size_t)(b * 1024 + row) * 768 + col] = f2bf(o_acc[jt][r] * inv);
    }
  }
}

// ---------------------------------------------------------------------------
extern "C" void kernel_launch(void* const* d_in, const int* in_sizes, int n_in,
                              void* d_out, int out_size, void* d_ws,
                              size_t ws_size, hipStream_t stream) {
  const float* x   = (const float*)d_in[0];
  const float* y   = (const float*)d_in[1];
  const float* rel = (const float*)d_in[2];
  const float* Wq  = (const float*)d_in[5];
  const float* Wk  = (const float*)d_in[6];
  const float* Wv  = (const float*)d_in[7];
  const float* Wp  = (const float*)d_in[8];
  const float* bp  = (const float*)d_in[9];
  float* out = (float*)d_out;

  const size_t nBNC = (size_t)Bb * Nn * Cc;  // 6291456
  const size_t nW = (size_t)Cc * Cc;         // 589824

  char* ws = (char*)d_ws;
  size_t off = 0;
  auto alloc = [&](size_t bytes) {
    char* p = ws + off;
    off += (bytes + 255) & ~(size_t)255;
    return p;
  };
  uint16_t* xb  = (uint16_t*)alloc(nBNC * 2);
  uint16_t* yb  = (uint16_t*)alloc(nBNC * 2);
  uint16_t* wqb = (uint16_t*)alloc(nW * 2);
  uint16_t* wkb = (uint16_t*)alloc(nW * 2);
  uint16_t* wvb = (uint16_t*)alloc(nW * 2);
  uint16_t* wpb = (uint16_t*)alloc(nW * 2);
  uint16_t* Qb  = (uint16_t*)alloc(nBNC * 2);
  uint16_t* Kb  = (uint16_t*)alloc(nBNC * 2);
  uint16_t* Vtb = (uint16_t*)alloc(nBNC * 2);
  uint16_t* AOb = (uint16_t*)alloc(nBNC * 2);

  // 1. conversions (2 launches)
  cvt2_kernel<<<dim3((int)(nBNC / 4 / 256), 2), 256, 0, stream>>>(
      x, y, xb, yb, (int)(nBNC / 4));
  cvtw_kernel<<<dim3((int)(nW / 4 / 256), 4), 256, 0, stream>>>(
      Wq, Wk, Wv, Wp, wqb, wkb, wvb, wpb, (int)(nW / 4));

  // 2. fused QKV projections
  qkv_kernel<<<dim3(18, 64), 256, 0, stream>>>(xb, yb, wqb, wkb, wvb, Qb, Kb,
                                               Vtb);

  // 3. attention
  attn_kernel<<<dim3(16, 64), 256, 0, stream>>>(Qb, Kb, Vtb, rel, AOb);

  // 4. output projection + bias
  proj_kernel<<<dim3(6, 64), 256, 0, stream>>>(AOb, wpb, out, bp);
}